// Round 1
// baseline (2272.908 us; speedup 1.0000x reference)
//
#include <hip/hip_runtime.h>

typedef __attribute__((ext_vector_type(8))) short short8;     // 8 bf16 = 4 VGPRs (MFMA A/B frag)
typedef __attribute__((ext_vector_type(16))) float f32x16;    // MFMA C/D frag (32x32)

__device__ __forceinline__ unsigned short f2bf(float f) {
  union { float f; unsigned u; } v; v.f = f;
  unsigned r = v.u + 0x7FFFu + ((v.u >> 16) & 1u);   // RNE
  return (unsigned short)(r >> 16);
}
__device__ __forceinline__ float bf2f(unsigned short h) {
  union { unsigned u; float f; } v; v.u = ((unsigned)h) << 16;
  return v.f;
}
// tanh(x) = 1 - 2/(e^{2x}+1); saturates correctly for |x| large, NaN-free for finite x.
__device__ __forceinline__ float tanh_fast(float x) {
  float e = __expf(2.0f * x);
  float r = __builtin_amdgcn_rcpf(e + 1.0f);
  return 1.0f - 2.0f * r;
}
// halfword index into a [32][64] bf16 LDS tile, XOR-swizzled to kill bank conflicts
__device__ __forceinline__ int swidx(int row, int col) {
  return row * 64 + (col ^ ((row & 7) << 3));
}

#define LDS_FENCE() asm volatile("s_waitcnt lgkmcnt(0)" ::: "memory")

__global__ __launch_bounds__(256, 2)
void ode_rk4_kernel(const float* __restrict__ x, const float* __restrict__ W1,
                    const float* __restrict__ b1, const float* __restrict__ W2,
                    const float* __restrict__ b2, float* __restrict__ out,
                    int nstrips)
{
  // W1^T, W2^T as bf16 [n][k], swizzled; per-wave double bounce buffers
  __shared__ __align__(16) unsigned short w1t[64 * 64];
  __shared__ __align__(16) unsigned short w2t[64 * 64];
  __shared__ __align__(16) unsigned short wbuf[4][2][32 * 64];

  const int tid  = threadIdx.x;
  const int wv   = tid >> 6;
  const int lane = tid & 63;
  const int hl   = lane >> 5;   // half-wave: selects k-half of frags / row+4 of C
  const int ln   = lane & 31;

  // ---- stage W^T into LDS as bf16 (value W[k][n] stored at [row=n]) ----
  for (int e = tid; e < 4096; e += 256) {
    int k = e >> 6, n = e & 63;
    w1t[swidx(n, k)] = f2bf(W1[e]);
    w2t[swidx(n, k)] = f2bf(W2[e]);
  }
  __syncthreads();

  // ---- per-lane B fragments: B[k][n], n = ln + 32*nt, k = kt*16 + 8*hl + i ----
  short8 w1f[4][2], w2f[4][2];
  #pragma unroll
  for (int kt = 0; kt < 4; ++kt)
    #pragma unroll
    for (int nt = 0; nt < 2; ++nt) {
      int n = ln + 32 * nt;
      int idx = n * 64 + ((kt * 16 + 8 * hl) ^ ((n & 7) << 3));
      w1f[kt][nt] = *(const short8*)&w1t[idx];
      w2f[kt][nt] = *(const short8*)&w2t[idx];
    }
  float b1v[2] = { b1[ln], b1[ln + 32] };
  float b2v[2] = { b2[ln], b2[ln + 32] };

  unsigned short* buf0 = &wbuf[wv][0][0];
  unsigned short* buf1 = &wbuf[wv][1][0];

  const int gw = gridDim.x * 4;
  int wid = blockIdx.x * 4 + wv;

  for (int s = wid; s < nstrips; s += gw) {
    const float* xs = x   + (size_t)s * (32 * 64);
    float*       os = out + (size_t)s * (32 * 64);

    // ---- load x directly in C-layout: row=(r&3)+8*(r>>2)+4*hl, col=ln+32*nt ----
    float xr[2][16];
    #pragma unroll
    for (int nt = 0; nt < 2; ++nt)
      #pragma unroll
      for (int r = 0; r < 16; ++r) {
        int row = (r & 3) + 8 * (r >> 2) + 4 * hl;
        xr[nt][r] = xs[row * 64 + ln + 32 * nt];
      }

    // ---- split x into bf16 hi/lo, scatter to LDS (swizzled; 2-way max = free) ----
    #pragma unroll
    for (int nt = 0; nt < 2; ++nt)
      #pragma unroll
      for (int r = 0; r < 16; ++r) {
        int row = (r & 3) + 8 * (r >> 2) + 4 * hl;
        int col = ln + 32 * nt;
        float v = xr[nt][r];
        unsigned short h = f2bf(v);
        buf0[swidx(row, col)] = h;
        buf1[swidx(row, col)] = f2bf(v - bf2f(h));
      }
    LDS_FENCE();

    // ---- preX = x@W1 + b1, split-bf16 (hi + lo), fp32 accum ----
    f32x16 preX[2];
    #pragma unroll
    for (int nt = 0; nt < 2; ++nt)
      #pragma unroll
      for (int i = 0; i < 16; ++i) preX[nt][i] = b1v[nt];

    #pragma unroll
    for (int kt = 0; kt < 4; ++kt) {
      int idx = ln * 64 + ((kt * 16 + 8 * hl) ^ ((ln & 7) << 3));
      short8 ah = *(const short8*)&buf0[idx];
      short8 al = *(const short8*)&buf1[idx];
      #pragma unroll
      for (int nt = 0; nt < 2; ++nt) {
        preX[nt] = __builtin_amdgcn_mfma_f32_32x32x16_bf16(ah, w1f[kt][nt], preX[nt], 0, 0, 0);
        preX[nt] = __builtin_amdgcn_mfma_f32_32x32x16_bf16(al, w1f[kt][nt], preX[nt], 0, 0, 0);
      }
    }

    f32x16 acc[2], kcur[2];

    // ---- 4 RK4 stages; stages 2-4 use linearity: pre = preX + c*(k_prev @ W1) ----
    #pragma unroll
    for (int stage = 0; stage < 4; ++stage) {
      f32x16 pre[2];
      if (stage == 0) {
        pre[0] = preX[0]; pre[1] = preX[1];
      } else {
        const float c = (stage == 3) ? 1.0f : 0.5f;
        #pragma unroll
        for (int nt = 0; nt < 2; ++nt)
          #pragma unroll
          for (int r = 0; r < 16; ++r) {
            int row = (r & 3) + 8 * (r >> 2) + 4 * hl;
            buf1[swidx(row, ln + 32 * nt)] = f2bf(kcur[nt][r]);
          }
        LDS_FENCE();
        f32x16 kw[2];
        #pragma unroll
        for (int nt = 0; nt < 2; ++nt)
          #pragma unroll
          for (int i = 0; i < 16; ++i) kw[nt][i] = 0.0f;
        #pragma unroll
        for (int kt = 0; kt < 4; ++kt) {
          int idx = ln * 64 + ((kt * 16 + 8 * hl) ^ ((ln & 7) << 3));
          short8 ak = *(const short8*)&buf1[idx];
          #pragma unroll
          for (int nt = 0; nt < 2; ++nt)
            kw[nt] = __builtin_amdgcn_mfma_f32_32x32x16_bf16(ak, w1f[kt][nt], kw[nt], 0, 0, 0);
        }
        pre[0] = preX[0] + c * kw[0];
        pre[1] = preX[1] + c * kw[1];
      }

      // h = tanh(pre) -> buf0 (bf16)
      #pragma unroll
      for (int nt = 0; nt < 2; ++nt)
        #pragma unroll
        for (int r = 0; r < 16; ++r) {
          int row = (r & 3) + 8 * (r >> 2) + 4 * hl;
          buf0[swidx(row, ln + 32 * nt)] = f2bf(tanh_fast(pre[nt][r]));
        }
      LDS_FENCE();

      // kcur = h @ W2 + b2
      #pragma unroll
      for (int nt = 0; nt < 2; ++nt)
        #pragma unroll
        for (int i = 0; i < 16; ++i) kcur[nt][i] = b2v[nt];
      #pragma unroll
      for (int kt = 0; kt < 4; ++kt) {
        int idx = ln * 64 + ((kt * 16 + 8 * hl) ^ ((ln & 7) << 3));
        short8 ahh = *(const short8*)&buf0[idx];
        #pragma unroll
        for (int nt = 0; nt < 2; ++nt)
          kcur[nt] = __builtin_amdgcn_mfma_f32_32x32x16_bf16(ahh, w2f[kt][nt], kcur[nt], 0, 0, 0);
      }

      if (stage == 0)      { acc[0]  = kcur[0];        acc[1]  = kcur[1]; }
      else if (stage == 3) { acc[0] += kcur[0];        acc[1] += kcur[1]; }
      else                 { acc[0] += 2.0f * kcur[0]; acc[1] += 2.0f * kcur[1]; }
    }

    // ---- out = x + acc/6 ----
    #pragma unroll
    for (int nt = 0; nt < 2; ++nt)
      #pragma unroll
      for (int r = 0; r < 16; ++r) {
        int row = (r & 3) + 8 * (r >> 2) + 4 * hl;
        os[row * 64 + ln + 32 * nt] = xr[nt][r] + (1.0f / 6.0f) * acc[nt][r];
      }
  }
}

extern "C" void kernel_launch(void* const* d_in, const int* in_sizes, int n_in,
                              void* d_out, int out_size, void* d_ws, size_t ws_size,
                              hipStream_t stream) {
  const float* x  = (const float*)d_in[0];
  const float* W1 = (const float*)d_in[1];
  const float* b1 = (const float*)d_in[2];
  const float* W2 = (const float*)d_in[3];
  const float* b2 = (const float*)d_in[4];
  float* out = (float*)d_out;
  int nstrips = in_sizes[0] / (32 * 64);   // rows / 32
  ode_rk4_kernel<<<1024, 256, 0, stream>>>(x, W1, b1, W2, b2, out, nstrips);
}

// Round 2
// 1088.528 us; speedup vs baseline: 2.0881x; 2.0881x over previous
//
#include <hip/hip_runtime.h>

typedef __attribute__((ext_vector_type(8))) short short8;   // 8 bf16 (MFMA A/B frag)
typedef __attribute__((ext_vector_type(16))) float f32x16;  // MFMA C/D frag (32x32)

union FragU { unsigned u[4]; short8 s8; };

__device__ __forceinline__ unsigned cvt_pk_bf16(float lo, float hi) {
  unsigned r;
  asm("v_cvt_pk_bf16_f32 %0, %1, %2" : "=v"(r) : "v"(lo), "v"(hi));
  return r;
}
// v_permlane32_swap_b32 modifies BOTH registers:
//   a' = {a[0:31] | b[0:31]},  b' = {a[32:63] | b[32:63]}
__device__ __forceinline__ void perm32_swap(unsigned& a, unsigned& b) {
  asm volatile("v_permlane32_swap_b32 %0, %1" : "+v"(a), "+v"(b));
}
__device__ __forceinline__ float bf_lo(unsigned u) { return __uint_as_float(u << 16); }
__device__ __forceinline__ float bf_hi(unsigned u) { return __uint_as_float(u & 0xffff0000u); }
__device__ __forceinline__ unsigned short f2bf(float f) {
  union { float f; unsigned u; } v; v.f = f;
  unsigned r = v.u + 0x7FFFu + ((v.u >> 16) & 1u);   // RNE
  return (unsigned short)(r >> 16);
}
__device__ __forceinline__ float tanh_fast(float x) {
  float e = __expf(2.0f * x);
  float r = __builtin_amdgcn_rcpf(e + 1.0f);
  return 1.0f - 2.0f * r;
}
__device__ __forceinline__ f32x16 zero16() {
  f32x16 z;
  #pragma unroll
  for (int i = 0; i < 16; ++i) z[i] = 0.0f;
  return z;
}

// p (packed bf16, P-layout) -> 4 B-frags, destructive on p.
// P[g][j] = p[2g+j]: lane(ln,hl) holds y[batch=ln][d = 8g+4hl+{0,1}] / {2,3}
__device__ __forceinline__ void build_frags(unsigned p[16], FragU F[4]) {
  #pragma unroll
  for (int kt = 0; kt < 4; ++kt) {
    perm32_swap(p[4*kt+0], p[4*kt+2]);
    perm32_swap(p[4*kt+1], p[4*kt+3]);
    F[kt].u[0] = p[4*kt+0]; F[kt].u[1] = p[4*kt+1];
    F[kt].u[2] = p[4*kt+2]; F[kt].u[3] = p[4*kt+3];
  }
}

__device__ __forceinline__ void matmul(const short8 wa[4][2], const short8 bA[2],
                                       const short8 ones, const FragU F[4],
                                       f32x16& c0, f32x16& c1) {
  f32x16 z = zero16();
  // rank-1 bias: C = b ⊗ 1
  c0 = __builtin_amdgcn_mfma_f32_32x32x16_bf16(bA[0], ones, z, 0, 0, 0);
  c1 = __builtin_amdgcn_mfma_f32_32x32x16_bf16(bA[1], ones, z, 0, 0, 0);
  #pragma unroll
  for (int kt = 0; kt < 4; ++kt) {
    c0 = __builtin_amdgcn_mfma_f32_32x32x16_bf16(wa[kt][0], F[kt].s8, c0, 0, 0, 0);
    c1 = __builtin_amdgcn_mfma_f32_32x32x16_bf16(wa[kt][1], F[kt].s8, c1, 0, 0, 0);
  }
}

__device__ __forceinline__ void tanh_pack(unsigned p[16], const f32x16& c0, const f32x16& c1) {
  #pragma unroll
  for (int g = 0; g < 8; ++g) {
    const f32x16& c = (g < 4) ? c0 : c1;
    int rg = g & 3;
    p[2*g+0] = cvt_pk_bf16(tanh_fast(c[4*rg+0]), tanh_fast(c[4*rg+1]));
    p[2*g+1] = cvt_pk_bf16(tanh_fast(c[4*rg+2]), tanh_fast(c[4*rg+3]));
  }
}

__device__ __forceinline__ void ypack(unsigned p[16], const unsigned xb[16], float cc,
                                      const f32x16& k0, const f32x16& k1) {
  #pragma unroll
  for (int g = 0; g < 8; ++g) {
    const f32x16& k = (g < 4) ? k0 : k1;
    int rg = g & 3;
    float y0 = bf_lo(xb[2*g+0]) + cc * k[4*rg+0];
    float y1 = bf_hi(xb[2*g+0]) + cc * k[4*rg+1];
    float y2 = bf_lo(xb[2*g+1]) + cc * k[4*rg+2];
    float y3 = bf_hi(xb[2*g+1]) + cc * k[4*rg+3];
    p[2*g+0] = cvt_pk_bf16(y0, y1);
    p[2*g+1] = cvt_pk_bf16(y2, y3);
  }
}

__global__ __launch_bounds__(256, 2)
void ode_rk4_kernel(const float* __restrict__ x, const float* __restrict__ W1,
                    const float* __restrict__ b1, const float* __restrict__ W2,
                    const float* __restrict__ b2, float* __restrict__ out,
                    int nstrips)
{
  const int tid  = threadIdx.x;
  const int lane = tid & 63;
  const int ln   = lane & 31;
  const int hl   = lane >> 5;
  const int wv   = tid >> 6;

  // ---- weight A-frags: wa[kt][mt] = W[16kt+8hl+i][ln+32mt], i=0..7 (bf16) ----
  short8 w1a[4][2], w2a[4][2];
  #pragma unroll
  for (int kt = 0; kt < 4; ++kt)
    #pragma unroll
    for (int mt = 0; mt < 2; ++mt) {
      int c = ln + 32*mt, kb = 16*kt + 8*hl;
      FragU f1, f2;
      #pragma unroll
      for (int j = 0; j < 4; ++j) {
        f1.u[j] = cvt_pk_bf16(W1[(kb+2*j)*64 + c], W1[(kb+2*j+1)*64 + c]);
        f2.u[j] = cvt_pk_bf16(W2[(kb+2*j)*64 + c], W2[(kb+2*j+1)*64 + c]);
      }
      w1a[kt][mt] = f1.s8; w2a[kt][mt] = f2.s8;
    }

  // ---- rank-1 bias frags: A = bias column (k=0), B = ones row (k=0) ----
  FragU onesF; onesF.u[0] = hl ? 0u : 0x3F80u; onesF.u[1] = onesF.u[2] = onesF.u[3] = 0u;
  short8 b1A[2], b2A[2];
  #pragma unroll
  for (int mt = 0; mt < 2; ++mt) {
    FragU fb1, fb2;
    fb1.u[0] = hl ? 0u : (unsigned)f2bf(b1[ln + 32*mt]);
    fb2.u[0] = hl ? 0u : (unsigned)f2bf(b2[ln + 32*mt]);
    fb1.u[1] = fb1.u[2] = fb1.u[3] = 0u;
    fb2.u[1] = fb2.u[2] = fb2.u[3] = 0u;
    b1A[mt] = fb1.s8; b2A[mt] = fb2.s8;
  }

  const int gw  = gridDim.x * 4;
  int wid       = blockIdx.x * 4 + wv;
  const int lnoff = ln * 16 + hl;   // float4 index of this lane's first group

  for (int s = wid; s < nstrips; s += gw) {
    const float4* xs4 = (const float4*)x   + (size_t)s * 512;
    float4*       os4 = (float4*)out       + (size_t)s * 512;

    // ---- load x (8 x float4 per lane), pack to bf16 P-layout ----
    unsigned xb[16];
    #pragma unroll
    for (int g = 0; g < 8; ++g) {
      float4 v = xs4[lnoff + 8*(g>>2) + 2*(g&3)];
      xb[2*g+0] = cvt_pk_bf16(v.x, v.y);
      xb[2*g+1] = cvt_pk_bf16(v.z, v.w);
    }

    f32x16 acc0, acc1, ct0, ct1;
    FragU F[4];
    unsigned p[16];

    // ---- stage 1: k1 = f(x) ----
    #pragma unroll
    for (int i = 0; i < 16; ++i) p[i] = xb[i];
    build_frags(p, F);
    matmul(w1a, b1A, onesF.s8, F, ct0, ct1);   // ct = x@W1 + b1
    tanh_pack(p, ct0, ct1);
    build_frags(p, F);
    matmul(w2a, b2A, onesF.s8, F, ct0, ct1);   // ct = k1
    acc0 = ct0; acc1 = ct1;

    // ---- stages 2..4 ----
    #pragma unroll
    for (int st = 1; st < 4; ++st) {
      const float cc = (st == 3) ? 1.0f : 0.5f;
      const float wc = (st == 3) ? 1.0f : 2.0f;
      ypack(p, xb, cc, ct0, ct1);              // y = x + cc*k_prev (bf16)
      build_frags(p, F);
      matmul(w1a, b1A, onesF.s8, F, ct0, ct1); // ct = y@W1 + b1
      tanh_pack(p, ct0, ct1);
      build_frags(p, F);
      matmul(w2a, b2A, onesF.s8, F, ct0, ct1); // ct = k_st
      acc0 += wc * ct0; acc1 += wc * ct1;
    }

    // ---- out = x + acc/6 ----
    #pragma unroll
    for (int g = 0; g < 8; ++g) {
      const f32x16& a = (g < 4) ? acc0 : acc1;
      int rg = g & 3;
      float4 o;
      o.x = bf_lo(xb[2*g+0]) + (1.0f/6.0f) * a[4*rg+0];
      o.y = bf_hi(xb[2*g+0]) + (1.0f/6.0f) * a[4*rg+1];
      o.z = bf_lo(xb[2*g+1]) + (1.0f/6.0f) * a[4*rg+2];
      o.w = bf_hi(xb[2*g+1]) + (1.0f/6.0f) * a[4*rg+3];
      os4[lnoff + 8*(g>>2) + 2*(g&3)] = o;
    }
  }
}

extern "C" void kernel_launch(void* const* d_in, const int* in_sizes, int n_in,
                              void* d_out, int out_size, void* d_ws, size_t ws_size,
                              hipStream_t stream) {
  const float* x  = (const float*)d_in[0];
  const float* W1 = (const float*)d_in[1];
  const float* b1 = (const float*)d_in[2];
  const float* W2 = (const float*)d_in[3];
  const float* b2 = (const float*)d_in[4];
  float* out = (float*)d_out;
  int nstrips = in_sizes[0] / 2048;   // rows / 32
  ode_rk4_kernel<<<1024, 256, 0, stream>>>(x, W1, b1, W2, b2, out, nstrips);
}